// Round 9
// baseline (165.510 us; speedup 1.0000x reference)
//
#include <hip/hip_runtime.h>

// LaplacianLoss on a fixed 512x512 grid mesh, B=32.
// Lv[b,(i,j)] = v - (1/deg)*sum(nbrs), nbrs = (i,j+-1),(i+-1,j),(i-1,j+1),(i+1,j-1)
// out = mean over (B,V) of |Lv|^2.
//
// R8 lesson: conditional loads in the row loop (halo predication, row-bound
// guards, pointer-indexed inv arrays) force the compiler to emit
// s_waitcnt vmcnt(0) before each use -> full latency exposed every iter
// (~17% duty, 40us plateau across R4-R8). R9: 100% branchless loop body —
// clamped row index + mrow multiply, halo via an always-executed float4 at
// per-lane constant offset dh, register ternaries for -1/deg — plus explicit
// depth-2 prefetch so vmcnt(N) pipelining is possible.

#define GH 512
#define GW 512
#define GV (GH * GW)
#define ROWF 1536                // floats per row
#define RQ 384                   // float4s per row = threads per block
#define RI 16                    // center rows per block
#define NITER (RI + 2)           // 18
#define NBLK (32 * 32)           // 1024 blocks

__global__ __launch_bounds__(RQ, 6) void lap_partial_kernel(
    const float* __restrict__ verts, float* __restrict__ partials) {
    const int bid   = blockIdx.x;
    const int batch = bid >> 5;
    const int chunk = bid & 31;
    const int i0    = chunk * RI;
    const int t     = threadIdx.x;       // owns floats [4t, 4t+4) of each row
    const int lane  = t & 63;
    const float* __restrict__ base = verts + (size_t)batch * (GV * 3) + 4 * t;

    // per-element -1/deg (mid/top/bottom row regimes), register-resident
    float invM[4], invT[4], invB[4];
    #pragma unroll
    for (int e = 0; e < 4; ++e) {
        const int q = 4 * t + e;
        const float jl = (q >= 3) ? 1.f : 0.f;
        const float jr = (q < ROWF - 3) ? 1.f : 0.f;
        invM[e] = -1.f / (2.f + 2.f * jl + 2.f * jr);
        invT[e] = -1.f / (1.f + 2.f * jl + jr);
        invB[e] = -1.f / (1.f + jl + 2.f * jr);
    }

    // halo: one always-executed float4 at per-lane constant offset
    const float mL = (lane == 0  && t > 0)      ? 1.f : 0.f;
    const float mR = (lane == 63 && t < RQ - 1) ? 1.f : 0.f;
    const int dh = (lane == 0) ? ((t > 0) ? -4 : 0)
                 : ((lane == 63) ? ((t < RQ - 1) ? 4 : 0) : 0);

    // depth-2 prefetch slots (rows i0-1 and i0)
    float4 Q0, H0, Q1, H1;
    {
        const float* rp0 = base + (size_t)max(i0 - 1, 0) * ROWF;
        Q0 = *(const float4*)rp0;
        H0 = *(const float4*)(rp0 + dh);
        const float* rp1 = base + (size_t)i0 * ROWF;
        Q1 = *(const float4*)rp1;
        H1 = *(const float4*)(rp1 + dh);
    }

    // carried combos: T2=T(c-1), T1=T(c), M1=M(c), C1=Q(c)
    float4 T2 = make_float4(0.f, 0.f, 0.f, 0.f), T1 = T2, M1 = T2, C1 = T2;
    float local = 0.f;

    #pragma unroll 2
    for (int k = 0; k < NITER; ++k) {
        const int r = i0 - 1 + k;                       // row consumed now
        const float mrow = (r >= 0 && r < GH) ? 1.f : 0.f;

        float4 Q = (k & 1) ? Q1 : Q0;
        float4 H = (k & 1) ? H1 : H0;

        // branchless prefetch of row r+2 into the freed slot
        {
            const int rn = min(max(r + 2, 0), GH - 1);
            const float* rp = base + (size_t)rn * ROWF;
            if (k & 1) { Q1 = *(const float4*)rp; H1 = *(const float4*)(rp + dh); }
            else       { Q0 = *(const float4*)rp; H0 = *(const float4*)(rp + dh); }
        }

        // apply row mask (OOB rows contribute zeros)
        Q.x *= mrow; Q.y *= mrow; Q.z *= mrow; Q.w *= mrow;
        const float mlr = mL * mrow, mrr = mR * mrow;
        const float hl0 = mlr * H.y, hl1 = mlr * H.z, hl2 = mlr * H.w;
        const float hr0 = mrr * H.x, hr1 = mrr * H.y, hr2 = mrr * H.z;

        // shifted vectors f[q-3]/f[q+3] via one-lane shuffles
        const float py = __shfl_up(Q.y, 1, 64);
        const float pz = __shfl_up(Q.z, 1, 64);
        const float pw = __shfl_up(Q.w, 1, 64);
        const float nx = __shfl_down(Q.x, 1, 64);
        const float ny = __shfl_down(Q.y, 1, 64);
        const float nz = __shfl_down(Q.z, 1, 64);

        float4 Qm3, Qp3;
        Qm3.x = (lane == 0)  ? hl0 : py;
        Qm3.y = (lane == 0)  ? hl1 : pz;
        Qm3.z = (lane == 0)  ? hl2 : pw;
        Qm3.w = Q.x;
        Qp3.x = Q.w;
        Qp3.y = (lane == 63) ? hr0 : nx;
        Qp3.z = (lane == 63) ? hr1 : ny;
        Qp3.w = (lane == 63) ? hr2 : nz;

        // combos: B = Q+Qm3, T = Q+Qp3, M = Qm3+Qp3
        float4 Bn, Tn, Mn;
        Bn.x = Q.x + Qm3.x; Bn.y = Q.y + Qm3.y; Bn.z = Q.z + Qm3.z; Bn.w = Q.w + Qm3.w;
        Tn.x = Q.x + Qp3.x; Tn.y = Q.y + Qp3.y; Tn.z = Q.z + Qp3.z; Tn.w = Q.w + Qp3.w;
        Mn.x = Qm3.x + Qp3.x; Mn.y = Qm3.y + Qp3.y; Mn.z = Qm3.z + Qp3.z; Mn.w = Qm3.w + Qp3.w;

        // finalize center c = i0+k-2: S = T(c-1) + M(c) + B(c+1)
        if (k >= 2) {
            const int c = i0 + k - 2;
            const bool ct = (c == 0), cb = (c == GH - 1);
            const float i0e = ct ? invT[0] : (cb ? invB[0] : invM[0]);
            const float i1e = ct ? invT[1] : (cb ? invB[1] : invM[1]);
            const float i2e = ct ? invT[2] : (cb ? invB[2] : invM[2]);
            const float i3e = ct ? invT[3] : (cb ? invB[3] : invM[3]);

            float s, lv;
            s = T2.x + M1.x + Bn.x; lv = fmaf(i0e, s, C1.x); local = fmaf(lv, lv, local);
            s = T2.y + M1.y + Bn.y; lv = fmaf(i1e, s, C1.y); local = fmaf(lv, lv, local);
            s = T2.z + M1.z + Bn.z; lv = fmaf(i2e, s, C1.z); local = fmaf(lv, lv, local);
            s = T2.w + M1.w + Bn.w; lv = fmaf(i3e, s, C1.w); local = fmaf(lv, lv, local);
        }

        // rotate (renamed by unroll-2)
        T2 = T1; T1 = Tn; M1 = Mn; C1 = Q;
    }

    // block reduction: wave shuffle -> LDS -> one store per block
    #pragma unroll
    for (int off = 32; off > 0; off >>= 1)
        local += __shfl_down(local, off, 64);

    __shared__ float wsum[6];
    const int wave = t >> 6;
    if (lane == 0) wsum[wave] = local;
    __syncthreads();
    if (t == 0) {
        float s = wsum[0];
        #pragma unroll
        for (int w = 1; w < 6; ++w) s += wsum[w];
        partials[bid] = s;
    }
}

__global__ __launch_bounds__(256) void lap_final_kernel(
    const float* __restrict__ partials, float* __restrict__ out, int nblk, int B) {
    float local = 0.0f;
    for (int k = threadIdx.x; k < nblk; k += 256)
        local += partials[k];

    #pragma unroll
    for (int off = 32; off > 0; off >>= 1)
        local += __shfl_down(local, off, 64);

    __shared__ float wsum[4];
    const int lane = threadIdx.x & 63;
    const int wid  = threadIdx.x >> 6;
    if (lane == 0) wsum[wid] = local;
    __syncthreads();

    if (threadIdx.x == 0) {
        const float s = wsum[0] + wsum[1] + wsum[2] + wsum[3];
        out[0] = s / ((float)B * (float)GV);
    }
}

extern "C" void kernel_launch(void* const* d_in, const int* in_sizes, int n_in,
                              void* d_out, int out_size, void* d_ws, size_t ws_size,
                              hipStream_t stream) {
    const float* verts = (const float*)d_in[0];
    float* out = (float*)d_out;
    float* partials = (float*)d_ws;            // 1024 floats = 4 KB

    const int B = in_sizes[0] / (GV * 3);      // 32

    lap_partial_kernel<<<NBLK, RQ, 0, stream>>>(verts, partials);
    lap_final_kernel<<<1, 256, 0, stream>>>(partials, out, NBLK, B);
}

// Round 10
// 159.972 us; speedup vs baseline: 1.0346x; 1.0346x over previous
//
#include <hip/hip_runtime.h>

// LaplacianLoss on a fixed 512x512 grid mesh, B=32.
// Lv[b,(i,j)] = v - (1/deg)*sum(nbrs), nbrs = (i,j+-1),(i+-1,j),(i-1,j+1),(i+1,j-1)
// out = mean over (B,V) of |Lv|^2.
//
// R9 lesson: depth-2 prefetch gives only ~1 iter (~200cyc) of runway vs ~900cyc
// cold-HBM latency (ws-poison sweeps L3 every replay) -> ~700cyc exposed stall
// per iter, the ~40us plateau. R10: depth-4 modular prefetch with NAMED slots
// (manual x4 unroll, compile-time slot selection, no dynamic indexing) -> 8
// outstanding loads/wave, ~3 iters of latency runway. Flattened-row float4 +
// one-lane shuffle scheme (verified R8/R9 math) otherwise unchanged.

#define GH 512
#define GW 512
#define GV (GH * GW)
#define ROWF 1536                // floats per row
#define RQ 384                   // float4s per row = threads per block
#define RI 16                    // center rows per block
#define NBLK (32 * 32)           // 1024 blocks

__global__ __launch_bounds__(RQ, 6) void lap_partial_kernel(
    const float* __restrict__ verts, float* __restrict__ partials) {
    const int bid   = blockIdx.x;
    const int batch = bid >> 5;
    const int chunk = bid & 31;
    const int i0    = chunk * RI;
    const int t     = threadIdx.x;       // owns floats [4t, 4t+4) of each row
    const int lane  = t & 63;
    const float* __restrict__ base = verts + (size_t)batch * (GV * 3) + 4 * t;

    // per-element -1/deg (mid/top/bottom row regimes)
    float invM[4], invT[4], invB[4];
    #pragma unroll
    for (int e = 0; e < 4; ++e) {
        const int q = 4 * t + e;
        const float jl = (q >= 3) ? 1.f : 0.f;
        const float jr = (q < ROWF - 3) ? 1.f : 0.f;
        invM[e] = -1.f / (2.f + 2.f * jl + 2.f * jr);
        invT[e] = -1.f / (1.f + 2.f * jl + jr);
        invB[e] = -1.f / (1.f + jl + 2.f * jr);
    }

    // halo: one always-executed float4 at per-lane constant offset
    const float mL = (lane == 0  && t > 0)      ? 1.f : 0.f;
    const float mR = (lane == 63 && t < RQ - 1) ? 1.f : 0.f;
    const int dh = (lane == 0) ? ((t > 0) ? -4 : 0)
                 : ((lane == 63) ? ((t < RQ - 1) ? 4 : 0) : 0);

    // depth-4 prefetch: named slots, rows i0-1 .. i0+2
    float4 Qs0, Qs1, Qs2, Qs3, Hs0, Hs1, Hs2, Hs3;
    {
        const float* rp0 = base + (size_t)max(i0 - 1, 0) * ROWF;
        Qs0 = *(const float4*)rp0; Hs0 = *(const float4*)(rp0 + dh);
        const float* rp1 = base + (size_t)(i0 + 0) * ROWF;
        Qs1 = *(const float4*)rp1; Hs1 = *(const float4*)(rp1 + dh);
        const float* rp2 = base + (size_t)(i0 + 1) * ROWF;
        Qs2 = *(const float4*)rp2; Hs2 = *(const float4*)(rp2 + dh);
        const float* rp3 = base + (size_t)(i0 + 2) * ROWF;
        Qs3 = *(const float4*)rp3; Hs3 = *(const float4*)(rp3 + dh);
    }

    // carried combos: T2=T(c-1), T1=T(c), M1=M(c), C1=Q(c)
    float4 T2 = make_float4(0.f, 0.f, 0.f, 0.f), T1 = T2, M1 = T2, C1 = T2;
    float local = 0.f;

    // iteration body; SLOT is a compile-time constant 0..3
#define ITER(K, QS, HS)                                                        \
    {                                                                          \
        const int k = (K);                                                     \
        const int r = i0 - 1 + k;                                              \
        const float mrow = (r >= 0 && r < GH) ? 1.f : 0.f;                     \
        float4 Q = QS;                                                         \
        const float4 H = HS;                                                   \
        /* refill slot with row i0+3+k (consumed at iter k+4), clamped */      \
        {                                                                      \
            const int rn = min(i0 + 3 + k, GH - 1);                            \
            const float* rp = base + (size_t)rn * ROWF;                        \
            QS = *(const float4*)rp;                                           \
            HS = *(const float4*)(rp + dh);                                    \
        }                                                                      \
        Q.x *= mrow; Q.y *= mrow; Q.z *= mrow; Q.w *= mrow;                    \
        const float mlr = mL * mrow, mrr = mR * mrow;                          \
        const float hl0 = mlr * H.y, hl1 = mlr * H.z, hl2 = mlr * H.w;         \
        const float hr0 = mrr * H.x, hr1 = mrr * H.y, hr2 = mrr * H.z;         \
        const float py = __shfl_up(Q.y, 1, 64);                                \
        const float pz = __shfl_up(Q.z, 1, 64);                                \
        const float pw = __shfl_up(Q.w, 1, 64);                                \
        const float nx = __shfl_down(Q.x, 1, 64);                              \
        const float ny = __shfl_down(Q.y, 1, 64);                              \
        const float nz = __shfl_down(Q.z, 1, 64);                              \
        float4 Qm3, Qp3;                                                       \
        Qm3.x = (lane == 0)  ? hl0 : py;                                       \
        Qm3.y = (lane == 0)  ? hl1 : pz;                                       \
        Qm3.z = (lane == 0)  ? hl2 : pw;                                       \
        Qm3.w = Q.x;                                                           \
        Qp3.x = Q.w;                                                           \
        Qp3.y = (lane == 63) ? hr0 : nx;                                       \
        Qp3.z = (lane == 63) ? hr1 : ny;                                       \
        Qp3.w = (lane == 63) ? hr2 : nz;                                       \
        float4 Bn, Tn, Mn;                                                     \
        Bn.x = Q.x + Qm3.x; Bn.y = Q.y + Qm3.y;                                \
        Bn.z = Q.z + Qm3.z; Bn.w = Q.w + Qm3.w;                                \
        Tn.x = Q.x + Qp3.x; Tn.y = Q.y + Qp3.y;                                \
        Tn.z = Q.z + Qp3.z; Tn.w = Q.w + Qp3.w;                                \
        Mn.x = Qm3.x + Qp3.x; Mn.y = Qm3.y + Qp3.y;                            \
        Mn.z = Qm3.z + Qp3.z; Mn.w = Qm3.w + Qp3.w;                            \
        if (k >= 2 && k < RI + 2) {                                            \
            const int c = i0 + k - 2;                                          \
            const bool ct = (c == 0), cb = (c == GH - 1);                      \
            const float i0e = ct ? invT[0] : (cb ? invB[0] : invM[0]);         \
            const float i1e = ct ? invT[1] : (cb ? invB[1] : invM[1]);         \
            const float i2e = ct ? invT[2] : (cb ? invB[2] : invM[2]);         \
            const float i3e = ct ? invT[3] : (cb ? invB[3] : invM[3]);         \
            float s, lv;                                                       \
            s = T2.x + M1.x + Bn.x; lv = fmaf(i0e, s, C1.x);                   \
            local = fmaf(lv, lv, local);                                       \
            s = T2.y + M1.y + Bn.y; lv = fmaf(i1e, s, C1.y);                   \
            local = fmaf(lv, lv, local);                                       \
            s = T2.z + M1.z + Bn.z; lv = fmaf(i2e, s, C1.z);                   \
            local = fmaf(lv, lv, local);                                       \
            s = T2.w + M1.w + Bn.w; lv = fmaf(i3e, s, C1.w);                   \
            local = fmaf(lv, lv, local);                                       \
        }                                                                      \
        T2 = T1; T1 = Tn; M1 = Mn; C1 = Q;                                     \
    }

    // 20 iterations (last 2 compute-masked; prefetches clamped/harmless)
    for (int kb = 0; kb < 20; kb += 4) {
        ITER(kb + 0, Qs0, Hs0);
        ITER(kb + 1, Qs1, Hs1);
        ITER(kb + 2, Qs2, Hs2);
        ITER(kb + 3, Qs3, Hs3);
    }
#undef ITER

    // block reduction: wave shuffle -> LDS -> one store per block
    #pragma unroll
    for (int off = 32; off > 0; off >>= 1)
        local += __shfl_down(local, off, 64);

    __shared__ float wsum[6];
    const int wave = t >> 6;
    if (lane == 0) wsum[wave] = local;
    __syncthreads();
    if (t == 0) {
        float s = wsum[0];
        #pragma unroll
        for (int w = 1; w < 6; ++w) s += wsum[w];
        partials[bid] = s;
    }
}

__global__ __launch_bounds__(256) void lap_final_kernel(
    const float* __restrict__ partials, float* __restrict__ out, int nblk, int B) {
    // nblk == 1024: each thread reads one float4
    float local = 0.0f;
    if (threadIdx.x * 4 < nblk) {
        const float4 p = ((const float4*)partials)[threadIdx.x];
        local = p.x + p.y + p.z + p.w;
    }

    #pragma unroll
    for (int off = 32; off > 0; off >>= 1)
        local += __shfl_down(local, off, 64);

    __shared__ float wsum[4];
    const int lane = threadIdx.x & 63;
    const int wid  = threadIdx.x >> 6;
    if (lane == 0) wsum[wid] = local;
    __syncthreads();

    if (threadIdx.x == 0) {
        const float s = wsum[0] + wsum[1] + wsum[2] + wsum[3];
        out[0] = s / ((float)B * (float)GV);
    }
}

extern "C" void kernel_launch(void* const* d_in, const int* in_sizes, int n_in,
                              void* d_out, int out_size, void* d_ws, size_t ws_size,
                              hipStream_t stream) {
    const float* verts = (const float*)d_in[0];
    float* out = (float*)d_out;
    float* partials = (float*)d_ws;            // 1024 floats = 4 KB

    const int B = in_sizes[0] / (GV * 3);      // 32

    lap_partial_kernel<<<NBLK, RQ, 0, stream>>>(verts, partials);
    lap_final_kernel<<<1, 256, 0, stream>>>(partials, out, NBLK, B);
}